// Round 11
// baseline (104.256 us; speedup 1.0000x reference)
//
#include <hip/hip_runtime.h>
#include <math.h>

#define TANFOV 1.0f

// AoS gaussian record: 3 x float4 (ORIGINAL gaussian order)
//   [0] = (tz, -0.5*conA, -conB, -0.5*conC)
//   [1] = (mx, my, op(0 if invalid), 0)
//   [2] = (c0, c1, c2, 0)
#define REC 12        // floats per gaussian
#define PRE_TB 64     // preprocess block size
#define TILE 8        // tile edge in pixels; K2 block = 64 threads = 1 wave
#define MAXSURV 2048  // worst-case survivors per tile (= N)

// ---------------------------------------------------------------------------
// Kernel 1: per-gaussian preprocessing (64-thread blocks for CU spread).
// Writes AoS record + conservative support bbox + tz + radii (to output).
// ---------------------------------------------------------------------------
__global__ __launch_bounds__(PRE_TB)
void preprocess_kernel(
    const float* __restrict__ xyz, const float* __restrict__ scaling,
    const float* __restrict__ rotation, const float* __restrict__ opacity,
    const float* __restrict__ fdc, const float* __restrict__ frest,
    const float* __restrict__ vm, const float* __restrict__ pm,
    const float* __restrict__ campos,
    const int* __restrict__ pH, const int* __restrict__ pW,
    float* __restrict__ pre, float4* __restrict__ bboxpre,
    float* __restrict__ tzarr, float* __restrict__ radii_out, int N)
{
    __shared__ float s_fr[PRE_TB * 45];
    int i0 = blockIdx.x * PRE_TB;
    int cnt = N - i0; if (cnt > PRE_TB) cnt = PRE_TB;
    for (int t = threadIdx.x; t < cnt * 45; t += PRE_TB)
        s_fr[t] = frest[(size_t)i0 * 45 + t];
    __syncthreads();

    int i = i0 + threadIdx.x;
    if (i >= N) return;
    float H = (float)*pH, W = (float)*pW;

    float px_ = xyz[i*3+0], py_ = xyz[i*3+1], pz_ = xyz[i*3+2];
    float s0 = expf(scaling[i*3+0]), s1 = expf(scaling[i*3+1]), s2 = expf(scaling[i*3+2]);
    float op = 1.f / (1.f + expf(-opacity[i]));

    float qw = rotation[i*4+0], qx = rotation[i*4+1], qy = rotation[i*4+2], qz = rotation[i*4+3];
    float qn = fmaxf(sqrtf(qw*qw + qx*qx + qy*qy + qz*qz), 1e-12f);
    qw /= qn; qx /= qn; qy /= qn; qz /= qn;

    float R00 = 1.f - 2.f*(qy*qy + qz*qz), R01 = 2.f*(qx*qy - qw*qz), R02 = 2.f*(qx*qz + qw*qy);
    float R10 = 2.f*(qx*qy + qw*qz), R11 = 1.f - 2.f*(qx*qx + qz*qz), R12 = 2.f*(qy*qz - qw*qx);
    float R20 = 2.f*(qx*qz - qw*qy), R21 = 2.f*(qy*qz + qw*qx), R22 = 1.f - 2.f*(qx*qx + qy*qy);

    float M00 = R00*s0, M01 = R01*s1, M02 = R02*s2;
    float M10 = R10*s0, M11 = R11*s1, M12 = R12*s2;
    float M20 = R20*s0, M21 = R21*s1, M22 = R22*s2;

    float S00 = M00*M00 + M01*M01 + M02*M02;
    float S01 = M00*M10 + M01*M11 + M02*M12;
    float S02 = M00*M20 + M01*M21 + M02*M22;
    float S11 = M10*M10 + M11*M11 + M12*M12;
    float S12 = M10*M20 + M11*M21 + M12*M22;
    float S22 = M20*M20 + M21*M21 + M22*M22;

    float t0 = px_*vm[0] + py_*vm[4] + pz_*vm[8]  + vm[12];
    float t1 = px_*vm[1] + py_*vm[5] + pz_*vm[9]  + vm[13];
    float tz = px_*vm[2] + py_*vm[6] + pz_*vm[10] + vm[14];

    float fx = W / (2.f * TANFOV), fy = H / (2.f * TANFOV);
    float lim = 1.3f * TANFOV;
    float tzs = (fabsf(tz) > 1e-6f) ? tz : 1e-6f;
    float txz = fminf(fmaxf(t0 / tzs, -lim), lim) * tzs;
    float tyz = fminf(fmaxf(t1 / tzs, -lim), lim) * tzs;
    float J00 = fx / tzs, J02 = -fx * txz / (tzs * tzs);
    float J11 = fy / tzs, J12 = -fy * tyz / (tzs * tzs);

    float T00 = J00*vm[0] + J02*vm[2];
    float T01 = J00*vm[4] + J02*vm[6];
    float T02 = J00*vm[8] + J02*vm[10];
    float T10 = J11*vm[1] + J12*vm[2];
    float T11 = J11*vm[5] + J12*vm[6];
    float T12 = J11*vm[9] + J12*vm[10];

    float u0 = S00*T00 + S01*T01 + S02*T02;
    float u1 = S01*T00 + S11*T01 + S12*T02;
    float u2 = S02*T00 + S12*T01 + S22*T02;
    float v0 = S00*T10 + S01*T11 + S02*T12;
    float v1 = S01*T10 + S11*T11 + S12*T12;
    float v2 = S02*T10 + S12*T11 + S22*T12;
    float a  = T00*u0 + T01*u1 + T02*u2 + 0.3f;
    float b  = T10*u0 + T11*u1 + T12*u2;
    float c  = T10*v0 + T11*v1 + T12*v2 + 0.3f;

    float det = a*c - b*b;
    bool valid = (tz > 0.2f) && (det > 0.f);
    float inv_det = 1.f / ((det > 0.f) ? det : 1.f);
    float conA = c * inv_det, conB = -b * inv_det, conC = a * inv_det;
    float mid = 0.5f * (a + c);
    float lam = mid + sqrtf(fmaxf(mid*mid - det, 0.1f));
    radii_out[i] = valid ? ceilf(3.f * sqrtf(lam)) : 0.f;

    float h0 = px_*pm[0] + py_*pm[4] + pz_*pm[8]  + pm[12];
    float h1 = px_*pm[1] + py_*pm[5] + pz_*pm[9]  + pm[13];
    float h3 = px_*pm[3] + py_*pm[7] + pz_*pm[11] + pm[15];
    float pw = 1.f / (h3 + 1e-7f);
    float mx = ((h0*pw + 1.f) * W - 1.f) * 0.5f;
    float my = ((h1*pw + 1.f) * H - 1.f) * 0.5f;

    float ddx = px_ - campos[0], ddy = py_ - campos[1], ddz = pz_ - campos[2];
    float dn = fmaxf(sqrtf(ddx*ddx + ddy*ddy + ddz*ddz), 1e-12f);
    float x = ddx/dn, y = ddy/dn, z = ddz/dn;
    float xx = x*x, yy = y*y, zz = z*z, xy = x*y, yz = y*z, xz = x*z;

    float basis[16];
    basis[0]  = 0.28209479177387814f;
    basis[1]  = -0.4886025119029199f * y;
    basis[2]  =  0.4886025119029199f * z;
    basis[3]  = -0.4886025119029199f * x;
    basis[4]  =  1.0925484305920792f * xy;
    basis[5]  = -1.0925484305920792f * yz;
    basis[6]  =  0.31539156525252005f * (2.f*zz - xx - yy);
    basis[7]  = -1.0925484305920792f * xz;
    basis[8]  =  0.5462742152960396f * (xx - yy);
    basis[9]  = -0.5900435899266435f * y * (3.f*xx - yy);
    basis[10] =  2.890611442640554f  * xy * z;
    basis[11] = -0.4570457994644658f * y * (4.f*zz - xx - yy);
    basis[12] =  0.3731763325901154f * z * (2.f*zz - 3.f*xx - 3.f*yy);
    basis[13] = -0.4570457994644658f * x * (4.f*zz - xx - yy);
    basis[14] =  1.445305721320277f  * z * (xx - yy);
    basis[15] = -0.5900435899266435f * x * (xx - 3.f*yy);

    const float* fr = &s_fr[threadIdx.x * 45];
    float col[3];
    #pragma unroll
    for (int ch = 0; ch < 3; ++ch) {
        float r = basis[0] * fdc[i*3 + ch];
        #pragma unroll
        for (int j = 1; j < 16; ++j)
            r += basis[j] * fr[(j-1)*3 + ch];
        col[ch] = fmaxf(r + 0.5f, 0.f);
    }

    float opv = valid ? op : 0.f;
    float4* rec = (float4*)(pre + (size_t)i * REC);
    rec[0] = make_float4(tz, -0.5f*conA, -conB, -0.5f*conC);
    rec[1] = make_float4(mx, my, opv, 0.f);
    rec[2] = make_float4(col[0], col[1], col[2], 0.f);

    float4 bb;
    if (opv > 1.f/255.f) {
        float Rr = 1.01f * sqrtf(2.f * logf(255.f * opv) * lam) + 1.f;
        bb = make_float4(mx - Rr, mx + Rr, my - Rr, my + Rr);
    } else {
        bb = make_float4(1e30f, -1e30f, 1e30f, -1e30f);   // empty
    }
    bboxpre[i] = bb;
    tzarr[i] = tz;
}

// ---------------------------------------------------------------------------
// Kernel 2: per-tile render. One 64-thread wave per 8x8 pixel tile
// (grid = 256 tiles -> full CU spread; single wave -> cheap barriers).
//  1) cull: 32 INDEPENDENT coalesced bbox loads -> hit bitmask (pipelines),
//     then 32 register-only ballot-compactions -> survivor indices in
//     original (stable) order.
//  2) gather survivor tz keys; bitonic-sort (tz, idx) pairs in LDS --
//     total order == jnp.argsort stable order. Non-survivors contribute
//     exactly 0, so blending survivors in this order is math-identical to
//     the reference full ordering.
//  3) blend in 64-survivor batches staged to LDS; T/c/d carried in regs.
// ---------------------------------------------------------------------------
__global__ __launch_bounds__(64)
void render_tiles_kernel(const float4* __restrict__ grec,
                         const float4* __restrict__ bbox,
                         const float* __restrict__ tzarr,
                         const int* __restrict__ pH,
                         const int* __restrict__ pW,
                         const float* __restrict__ bg,
                         float* __restrict__ out, int N, int HW)
{
    __shared__ float  s_key[MAXSURV];
    __shared__ int    s_idx[MAXSURV];
    __shared__ float4 s_rec[3 * 64];

    const int tid = threadIdx.x;
    int W = *pW, H = *pH;
    int tilesX = (W + TILE - 1) / TILE;
    int tileX = blockIdx.x % tilesX;
    int tileY = blockIdx.x / tilesX;
    int px = tileX * TILE + (tid & (TILE - 1));
    int py = tileY * TILE + (tid / TILE);
    float fpx = (float)px, fpy = (float)py;
    float ftx0 = (float)(tileX * TILE), ftx1 = ftx0 + (float)(TILE - 1);
    float fty0 = (float)(tileY * TILE), fty1 = fty0 + (float)(TILE - 1);

    // ---- 1) cull: independent loads first, compaction after ----
    int NI = (N + 63) >> 6;                       // 32 for N=2048
    unsigned long long hm = 0ull;
    for (int it = 0; it < NI; ++it) {
        int i = (it << 6) + tid;
        bool hit = false;
        if (i < N) {
            float4 bb = bbox[i];                  // coalesced dwordx4
            hit = (bb.x <= ftx1) && (bb.y >= ftx0) &&
                  (bb.z <= fty1) && (bb.w >= fty0);
        }
        hm |= (hit ? 1ull : 0ull) << it;
    }
    int K = 0;
    for (int it = 0; it < NI; ++it) {
        bool hit = (hm >> it) & 1;
        unsigned long long m = __ballot(hit);
        if (hit) {
            int pos = __popcll(m & ((1ull << tid) - 1ull));
            s_idx[K + pos] = (it << 6) + tid;
        }
        K += __popcll(m);
    }
    __syncthreads();

    float T = 1.f, c0 = 0.f, c1 = 0.f, c2 = 0.f, d = 0.f;

    if (K > 0) {
        // ---- 2) gather keys, pad, bitonic sort (tz, idx) ascending ----
        for (int j = tid; j < K; j += 64) s_key[j] = tzarr[s_idx[j]];
        int KP = 64; while (KP < K) KP <<= 1;
        for (int j = K + tid; j < KP; j += 64) {
            s_key[j] = 3.4e38f; s_idx[j] = 0x7FFFFFFF;
        }
        __syncthreads();

        for (int kk = 2; kk <= KP; kk <<= 1) {
            for (int j = kk >> 1; j > 0; j >>= 1) {
                for (int e = tid; e < KP; e += 64) {
                    int p = e ^ j;
                    if (p > e) {
                        float ka = s_key[e], kb = s_key[p];
                        int   ia = s_idx[e], ib = s_idx[p];
                        bool lt = (ka < kb) || (ka == kb && ia < ib);
                        bool up = ((e & kk) == 0);
                        if (lt != up) {
                            s_key[e] = kb; s_key[p] = ka;
                            s_idx[e] = ib; s_idx[p] = ia;
                        }
                    }
                }
                __syncthreads();
            }
        }

        // ---- 3) blend in 64-survivor batches ----
        for (int b0 = 0; b0 < K; b0 += 64) {
            int nb = K - b0; if (nb > 64) nb = 64;
            for (int t = tid; t < 3 * nb; t += 64) {
                int s = t / 3, e = t - 3 * s;
                s_rec[t] = grec[3 * s_idx[b0 + s] + e];
            }
            __syncthreads();
            for (int s = 0; s < nb; ++s) {
                float4 pA = s_rec[3*s+0];   // tz, a2, b2, c2
                float4 pB = s_rec[3*s+1];   // mx, my, op, -
                float4 pC = s_rec[3*s+2];   // rgb
                float dx = fpx - pB.x, dy = fpy - pB.y;
                float power = pA.y*dx*dx + pA.w*dy*dy + pA.z*dx*dy;
                float alpha = fminf(0.99f, pB.z * __expf(fminf(power, 0.f)));
                bool keep = (power <= 0.f) && (alpha >= 1.f/255.f);
                float aeff = keep ? alpha : 0.f;
                float w = aeff * T;
                c0 = fmaf(w, pC.x, c0);
                c1 = fmaf(w, pC.y, c1);
                c2 = fmaf(w, pC.z, c2);
                d  = fmaf(w, pA.x, d);
                T  = T - aeff * T;
            }
            __syncthreads();
        }
    }

    if (px < W && py < H) {
        int pix = py * W + px;
        out[0*HW+pix] = c0 + T*bg[0];
        out[1*HW+pix] = c1 + T*bg[1];
        out[2*HW+pix] = c2 + T*bg[2];
        out[3*HW+pix] = d;
        out[4*HW+pix] = 1.f - T;
    }
}

extern "C" void kernel_launch(void* const* d_in, const int* in_sizes, int n_in,
                              void* d_out, int out_size, void* d_ws, size_t ws_size,
                              hipStream_t stream) {
    const float* xyz      = (const float*)d_in[0];
    const float* scaling  = (const float*)d_in[1];
    const float* rotation = (const float*)d_in[2];
    const float* opacity  = (const float*)d_in[3];
    const float* fdc      = (const float*)d_in[4];
    const float* frest    = (const float*)d_in[5];
    const float* vm       = (const float*)d_in[6];
    const float* pm       = (const float*)d_in[7];
    const float* campos   = (const float*)d_in[8];
    const float* bg       = (const float*)d_in[9];
    const int*   pH       = (const int*)d_in[10];
    const int*   pW       = (const int*)d_in[11];

    int N  = in_sizes[0] / 3;
    int HW = (out_size - N) / 5;

    // 128x128 image, 8x8 tiles -> 256 tile blocks (computed on device from W
    // for addressing; grid uses HW assuming W==H==sqrt(HW) not required:
    // grid = ceil(HW / 64) works since tiles exactly partition the image
    // when W,H are multiples of 8 -- true here (128x128).
    int NTILE = HW / (TILE * TILE);

    // ws layout: pre REC*N floats | bboxpre 4N | tzarr N
    float*  ws      = (float*)d_ws;
    float*  pre     = ws;
    float4* bboxpre = (float4*)(pre + (size_t)REC * N);
    float*  tzarr   = (float*)(bboxpre + N);

    float* out   = (float*)d_out;
    float* radii = out + (size_t)5 * HW;

    preprocess_kernel<<<(N + PRE_TB - 1) / PRE_TB, PRE_TB, 0, stream>>>(
        xyz, scaling, rotation, opacity, fdc, frest, vm, pm, campos, pH, pW,
        pre, bboxpre, tzarr, radii, N);
    render_tiles_kernel<<<NTILE, 64, 0, stream>>>(
        (const float4*)pre, bboxpre, tzarr, pH, pW, bg, out, N, HW);
}

// Round 12
// 34.400 us; speedup vs baseline: 3.0307x; 3.0307x over previous
//
#include <hip/hip_runtime.h>
#include <math.h>

#define TANFOV 1.0f

// AoS gaussian record: 3 x float4 (ORIGINAL gaussian order; depth order via
// per-block perm windows rebuilt from rankpart)
//   [0] = (tz, -0.5*conA, -conB, -0.5*conC)
//   [1] = (mx, my, op(0 if invalid), 0)
//   [2] = (c0, c1, c2, 0)
#define REC   12     // floats per gaussian
#define CHG   256    // gaussians per depth chunk (== block size)
#define SEG_L 256    // sort segment length (NJ = N/SEG_L = 8 partials)

// ---------------------------------------------------------------------------
// Kernel A: role-split fused launch (no data dependency between roles):
//   blocks [0, NB)           : preprocess 256 gaussians each
//   blocks [NB, NB + NB*NJ)  : sort partial-rank count (col, seg)
// Count computes tz directly from xyz+vm (6 flops), independent of the
// preprocess role's output -- that's what makes the fusion legal.
// ---------------------------------------------------------------------------
__global__ __launch_bounds__(256)
void pre_count_kernel(
    const float* __restrict__ xyz, const float* __restrict__ scaling,
    const float* __restrict__ rotation, const float* __restrict__ opacity,
    const float* __restrict__ fdc, const float* __restrict__ frest,
    const float* __restrict__ vm, const float* __restrict__ pm,
    const float* __restrict__ campos,
    const int* __restrict__ pH, const int* __restrict__ pW,
    float* __restrict__ pre, float4* __restrict__ bboxpre,
    int* __restrict__ rankpart, float* __restrict__ radii_out,
    int N, int NB, int NJ)
{
    __shared__ float s_fr[256 * 45];      // preprocess: frest staging (46 KB)
    const int tid = threadIdx.x;
    const int bid = blockIdx.x;

    if (bid >= NB) {
        // ================= role: sort partial-rank count =================
        float* s_tz = s_fr;               // alias (SEG_L floats used)
        int t = bid - NB;
        int col = t / NJ, seg = t - col * NJ;
        int base = seg * SEG_L;
        float c2 = vm[2], c6 = vm[6], c10 = vm[10], c14 = vm[14];
        if (tid < SEG_L) {
            int j = base + tid;
            s_tz[tid] = (j < N)
                ? xyz[j*3+0]*c2 + xyz[j*3+1]*c6 + xyz[j*3+2]*c10 + c14
                : 3.4e38f;
        }
        __syncthreads();

        int i = col * 256 + tid;
        if (i < N) {
            float key = xyz[i*3+0]*c2 + xyz[i*3+1]*c6 + xyz[i*3+2]*c10 + c14;
            int cnt = 0;
            #pragma unroll 8
            for (int j = 0; j < SEG_L; j += 4) {
                float4 v = *reinterpret_cast<float4*>(&s_tz[j]);
                cnt += (v.x < key) || (v.x == key && (base + j)     < i);
                cnt += (v.y < key) || (v.y == key && (base + j + 1) < i);
                cnt += (v.z < key) || (v.z == key && (base + j + 2) < i);
                cnt += (v.w < key) || (v.w == key && (base + j + 3) < i);
            }
            rankpart[seg * N + i] = cnt;
        }
        return;
    }

    // ================= role: preprocess =================
    int i0 = bid * 256;
    int cnt = N - i0; if (cnt > 256) cnt = 256;
    for (int t = tid; t < cnt * 45; t += 256)
        s_fr[t] = frest[(size_t)i0 * 45 + t];
    __syncthreads();

    int i = i0 + tid;
    if (i >= N) return;
    float H = (float)*pH, W = (float)*pW;

    float px_ = xyz[i*3+0], py_ = xyz[i*3+1], pz_ = xyz[i*3+2];
    float s0 = expf(scaling[i*3+0]), s1 = expf(scaling[i*3+1]), s2 = expf(scaling[i*3+2]);
    float op = 1.f / (1.f + expf(-opacity[i]));

    float qw = rotation[i*4+0], qx = rotation[i*4+1], qy = rotation[i*4+2], qz = rotation[i*4+3];
    float qn = fmaxf(sqrtf(qw*qw + qx*qx + qy*qy + qz*qz), 1e-12f);
    qw /= qn; qx /= qn; qy /= qn; qz /= qn;

    float R00 = 1.f - 2.f*(qy*qy + qz*qz), R01 = 2.f*(qx*qy - qw*qz), R02 = 2.f*(qx*qz + qw*qy);
    float R10 = 2.f*(qx*qy + qw*qz), R11 = 1.f - 2.f*(qx*qx + qz*qz), R12 = 2.f*(qy*qz - qw*qx);
    float R20 = 2.f*(qx*qz - qw*qy), R21 = 2.f*(qy*qz + qw*qx), R22 = 1.f - 2.f*(qx*qx + qy*qy);

    float M00 = R00*s0, M01 = R01*s1, M02 = R02*s2;
    float M10 = R10*s0, M11 = R11*s1, M12 = R12*s2;
    float M20 = R20*s0, M21 = R21*s1, M22 = R22*s2;

    float S00 = M00*M00 + M01*M01 + M02*M02;
    float S01 = M00*M10 + M01*M11 + M02*M12;
    float S02 = M00*M20 + M01*M21 + M02*M22;
    float S11 = M10*M10 + M11*M11 + M12*M12;
    float S12 = M10*M20 + M11*M21 + M12*M22;
    float S22 = M20*M20 + M21*M21 + M22*M22;

    float t0 = px_*vm[0] + py_*vm[4] + pz_*vm[8]  + vm[12];
    float t1 = px_*vm[1] + py_*vm[5] + pz_*vm[9]  + vm[13];
    float tz = px_*vm[2] + py_*vm[6] + pz_*vm[10] + vm[14];

    float fx = W / (2.f * TANFOV), fy = H / (2.f * TANFOV);
    float lim = 1.3f * TANFOV;
    float tzs = (fabsf(tz) > 1e-6f) ? tz : 1e-6f;
    float txz = fminf(fmaxf(t0 / tzs, -lim), lim) * tzs;
    float tyz = fminf(fmaxf(t1 / tzs, -lim), lim) * tzs;
    float J00 = fx / tzs, J02 = -fx * txz / (tzs * tzs);
    float J11 = fy / tzs, J12 = -fy * tyz / (tzs * tzs);

    float T00 = J00*vm[0] + J02*vm[2];
    float T01 = J00*vm[4] + J02*vm[6];
    float T02 = J00*vm[8] + J02*vm[10];
    float T10 = J11*vm[1] + J12*vm[2];
    float T11 = J11*vm[5] + J12*vm[6];
    float T12 = J11*vm[9] + J12*vm[10];

    float u0 = S00*T00 + S01*T01 + S02*T02;
    float u1 = S01*T00 + S11*T01 + S12*T02;
    float u2 = S02*T00 + S12*T01 + S22*T02;
    float v0 = S00*T10 + S01*T11 + S02*T12;
    float v1 = S01*T10 + S11*T11 + S12*T12;
    float v2 = S02*T10 + S12*T11 + S22*T12;
    float a  = T00*u0 + T01*u1 + T02*u2 + 0.3f;
    float b  = T10*u0 + T11*u1 + T12*u2;
    float c  = T10*v0 + T11*v1 + T12*v2 + 0.3f;

    float det = a*c - b*b;
    bool valid = (tz > 0.2f) && (det > 0.f);
    float inv_det = 1.f / ((det > 0.f) ? det : 1.f);
    float conA = c * inv_det, conB = -b * inv_det, conC = a * inv_det;
    float mid = 0.5f * (a + c);
    float lam = mid + sqrtf(fmaxf(mid*mid - det, 0.1f));
    radii_out[i] = valid ? ceilf(3.f * sqrtf(lam)) : 0.f;

    float h0 = px_*pm[0] + py_*pm[4] + pz_*pm[8]  + pm[12];
    float h1 = px_*pm[1] + py_*pm[5] + pz_*pm[9]  + pm[13];
    float h3 = px_*pm[3] + py_*pm[7] + pz_*pm[11] + pm[15];
    float pw = 1.f / (h3 + 1e-7f);
    float mx = ((h0*pw + 1.f) * W - 1.f) * 0.5f;
    float my = ((h1*pw + 1.f) * H - 1.f) * 0.5f;

    float ddx = px_ - campos[0], ddy = py_ - campos[1], ddz = pz_ - campos[2];
    float dn = fmaxf(sqrtf(ddx*ddx + ddy*ddy + ddz*ddz), 1e-12f);
    float x = ddx/dn, y = ddy/dn, z = ddz/dn;
    float xx = x*x, yy = y*y, zz = z*z, xy = x*y, yz = y*z, xz = x*z;

    float basis[16];
    basis[0]  = 0.28209479177387814f;
    basis[1]  = -0.4886025119029199f * y;
    basis[2]  =  0.4886025119029199f * z;
    basis[3]  = -0.4886025119029199f * x;
    basis[4]  =  1.0925484305920792f * xy;
    basis[5]  = -1.0925484305920792f * yz;
    basis[6]  =  0.31539156525252005f * (2.f*zz - xx - yy);
    basis[7]  = -1.0925484305920792f * xz;
    basis[8]  =  0.5462742152960396f * (xx - yy);
    basis[9]  = -0.5900435899266435f * y * (3.f*xx - yy);
    basis[10] =  2.890611442640554f  * xy * z;
    basis[11] = -0.4570457994644658f * y * (4.f*zz - xx - yy);
    basis[12] =  0.3731763325901154f * z * (2.f*zz - 3.f*xx - 3.f*yy);
    basis[13] = -0.4570457994644658f * x * (4.f*zz - xx - yy);
    basis[14] =  1.445305721320277f  * z * (xx - yy);
    basis[15] = -0.5900435899266435f * x * (xx - 3.f*yy);

    const float* fr = &s_fr[tid * 45];
    float col[3];
    #pragma unroll
    for (int ch = 0; ch < 3; ++ch) {
        float r = basis[0] * fdc[i*3 + ch];
        #pragma unroll
        for (int j = 1; j < 16; ++j)
            r += basis[j] * fr[(j-1)*3 + ch];
        col[ch] = fmaxf(r + 0.5f, 0.f);
    }

    float opv = valid ? op : 0.f;
    float4* rec = (float4*)(pre + (size_t)i * REC);
    rec[0] = make_float4(tz, -0.5f*conA, -conB, -0.5f*conC);
    rec[1] = make_float4(mx, my, opv, 0.f);
    rec[2] = make_float4(col[0], col[1], col[2], 0.f);

    float4 bb;
    if (opv > 1.f/255.f) {
        float Rr = 1.01f * sqrtf(2.f * logf(255.f * opv) * lam) + 1.f;
        bb = make_float4(mx - Rr, mx + Rr, my - Rr, my + Rr);
    } else {
        bb = make_float4(1e30f, -1e30f, 1e30f, -1e30f);   // empty
    }
    bboxpre[i] = bb;
}

// ---------------------------------------------------------------------------
// Kernel B: tile-cull blend with IN-BLOCK perm window. Block = (16x16 tile,
// 256-slot depth chunk). Step 0: each thread computes the exact rank of 8
// gaussians (sum of NJ=8 partials; 64 coalesced independent L2 loads) and
// scatters the ones whose rank falls in this chunk's window into s_perm
// (bijective -> every in-range slot written, no atomics). Then cull /
// stage / blend. Removes the separate scatter kernel + global perm array.
// Assumes N <= 8*256 (true: N=2048).
// part layout: field*(G*HW) + chunk*HW + pix; fields 0..2 color, 3 depth, 4 T
// ---------------------------------------------------------------------------
__global__ __launch_bounds__(256)
void blend1_kernel(const float4* __restrict__ grec,
                   const float4* __restrict__ bbox,
                   const int* __restrict__ rankpart,
                   const int* __restrict__ pW,
                   float* __restrict__ part,
                   int N, int HW, int G, int NJ)
{
    __shared__ int    s_perm[CHG];
    __shared__ int    s_cnt[4];
    __shared__ int    s_idx[CHG];
    __shared__ float4 s_rec[3 * CHG];

    const int tid = threadIdx.x;
    const int chunk = blockIdx.y;
    const int g0 = chunk * CHG;

    // ---- Step 0: build this chunk's perm window ----
    int rk[8];
    #pragma unroll
    for (int b = 0; b < 8; ++b) rk[b] = 0;
    for (int s = 0; s < NJ; ++s) {
        const int* rp = rankpart + s * N;
        #pragma unroll
        for (int b = 0; b < 8; ++b) {
            int i = (b << 8) + tid;
            rk[b] += (i < N) ? rp[i] : 0;
        }
    }
    #pragma unroll
    for (int b = 0; b < 8; ++b) {
        int i = (b << 8) + tid;
        if (i < N) {
            unsigned r = (unsigned)(rk[b] - g0);
            if (r < (unsigned)CHG) s_perm[r] = i;
        }
    }

    int W = *pW;
    int tilesX = (W + 15) >> 4;
    int tileX = blockIdx.x % tilesX;
    int tileY = blockIdx.x / tilesX;
    int px = (tileX << 4) + (tid & 15);
    int py = (tileY << 4) + (tid >> 4);
    int pix = py * W + px;
    float fpx = (float)px, fpy = (float)py;
    float ftx0 = (float)(tileX << 4), ftx1 = ftx0 + 15.f;
    float fty0 = (float)(tileY << 4), fty1 = fty0 + 15.f;
    __syncthreads();

    // ---- cull: one sorted slot per thread (depth order via s_perm) ----
    int g = g0 + tid;
    bool hit = false;
    int orig = 0;
    if (g < N) {
        orig = s_perm[tid];
        float4 bb = bbox[orig];              // gathered 16B load (L2)
        hit = (bb.x <= ftx1) && (bb.y >= ftx0) &&
              (bb.z <= fty1) && (bb.w >= fty0);
    }
    unsigned long long m = __ballot(hit);
    int lane = tid & 63, wv = tid >> 6;
    int pos = __popcll(m & ((1ull << lane) - 1ull));
    if (lane == 0) s_cnt[wv] = __popcll(m);
    __syncthreads();
    int total = s_cnt[0] + s_cnt[1] + s_cnt[2] + s_cnt[3];
    int off = 0;
    for (int w = 0; w < wv; ++w) off += s_cnt[w];
    if (hit) s_idx[off + pos] = orig;
    __syncthreads();

    // ---- stage survivor records (parallel gathers) ----
    for (int k = tid; k < 3 * total; k += CHG) {
        int s = k / 3, e = k - 3 * s;
        s_rec[k] = grec[3 * s_idx[s] + e];
    }
    __syncthreads();

    // ---- blend over survivors (depth order preserved) ----
    float T = 1.f, c0 = 0.f, c1 = 0.f, c2 = 0.f, d = 0.f;
    for (int s = 0; s < total; ++s) {
        float4 pA = s_rec[3*s+0];   // tz, a2, b2, c2
        float4 pB = s_rec[3*s+1];   // mx, my, op, -
        float4 pC = s_rec[3*s+2];   // rgb
        float dx = fpx - pB.x, dy = fpy - pB.y;
        float power = pA.y*dx*dx + pA.w*dy*dy + pA.z*dx*dy;
        float alpha = fminf(0.99f, pB.z * __expf(fminf(power, 0.f)));
        bool keep = (power <= 0.f) && (alpha >= 1.f/255.f);
        float aeff = keep ? alpha : 0.f;
        float w = aeff * T;
        c0 = fmaf(w, pC.x, c0);
        c1 = fmaf(w, pC.y, c1);
        c2 = fmaf(w, pC.z, c2);
        d  = fmaf(w, pA.x, d);
        T  = T - aeff * T;
    }
    if (pix < HW) {
        int o = chunk * HW + pix;
        int S = G * HW;
        part[0*S+o] = c0; part[1*S+o] = c1; part[2*S+o] = c2;
        part[3*S+o] = d;  part[4*S+o] = T;
    }
}

// ---------------------------------------------------------------------------
// Kernel C: combine chunks per pixel, write final outputs.
// out layout: color[3][HW], depth[HW], amap[HW]  (radii written by kernel A)
// ---------------------------------------------------------------------------
__global__ void blend2_kernel(const float* __restrict__ part,
                              const float* __restrict__ bg,
                              float* __restrict__ out, int HW, int G)
{
    int pix = blockIdx.x * blockDim.x + threadIdx.x;
    if (pix >= HW) return;
    int S = G * HW;
    float T = 1.f, c0 = 0.f, c1 = 0.f, c2 = 0.f, d = 0.f;
    for (int k = 0; k < G; ++k) {
        int o = k * HW + pix;
        c0 += T * part[0*S+o];
        c1 += T * part[1*S+o];
        c2 += T * part[2*S+o];
        d  += T * part[3*S+o];
        T  *= part[4*S+o];
    }
    out[0*HW+pix] = c0 + T*bg[0];
    out[1*HW+pix] = c1 + T*bg[1];
    out[2*HW+pix] = c2 + T*bg[2];
    out[3*HW+pix] = d;
    out[4*HW+pix] = 1.f - T;
}

extern "C" void kernel_launch(void* const* d_in, const int* in_sizes, int n_in,
                              void* d_out, int out_size, void* d_ws, size_t ws_size,
                              hipStream_t stream) {
    const float* xyz      = (const float*)d_in[0];
    const float* scaling  = (const float*)d_in[1];
    const float* rotation = (const float*)d_in[2];
    const float* opacity  = (const float*)d_in[3];
    const float* fdc      = (const float*)d_in[4];
    const float* frest    = (const float*)d_in[5];
    const float* vm       = (const float*)d_in[6];
    const float* pm       = (const float*)d_in[7];
    const float* campos   = (const float*)d_in[8];
    const float* bg       = (const float*)d_in[9];
    const int*   pH       = (const int*)d_in[10];
    const int*   pW       = (const int*)d_in[11];

    int N  = in_sizes[0] / 3;
    int HW = (out_size - N) / 5;
    int G  = (N + CHG - 1) / CHG;       // 8 chunks
    int NJ = (N + SEG_L - 1) / SEG_L;   // 8 segments
    int NB = (N + 255) / 256;           // 8 columns
    int NT = (HW + 255) / 256;          // 64 tiles

    // ws layout:
    //   pre     : REC*N floats
    //   bboxpre : 4*N floats
    //   rankpart: NJ*N ints
    //   part    : 5*G*HW floats
    float*  ws       = (float*)d_ws;
    float*  pre      = ws;
    float4* bboxpre  = (float4*)(pre + (size_t)REC * N);
    int*    rankpart = (int*)(bboxpre + N);
    float*  part     = (float*)(rankpart + (size_t)NJ * N);

    float* out   = (float*)d_out;
    float* radii = out + (size_t)5 * HW;

    // Kernel A: preprocess (blocks 0..NB-1) || count (blocks NB..NB+NB*NJ-1)
    pre_count_kernel<<<NB + NB * NJ, 256, 0, stream>>>(
        xyz, scaling, rotation, opacity, fdc, frest, vm, pm, campos, pH, pW,
        pre, bboxpre, rankpart, radii, N, NB, NJ);
    // Kernel B: tile-cull blend with in-block perm window
    dim3 bgrid(NT, G);
    blend1_kernel<<<bgrid, CHG, 0, stream>>>(
        (const float4*)pre, bboxpre, rankpart, pW, part, N, HW, G, NJ);
    // Kernel C: combine
    blend2_kernel<<<NT, 256, 0, stream>>>(part, bg, out, HW, G);
}

// Round 13
// 33.962 us; speedup vs baseline: 3.0698x; 1.0129x over previous
//
#include <hip/hip_runtime.h>
#include <math.h>

#define TANFOV 1.0f

// AoS gaussian record: 3 x float4 (ORIGINAL gaussian order; depth order via
// the perm[] index array built by scatter_kernel)
//   [0] = (tz, -0.5*conA, -conB, -0.5*conC)
//   [1] = (mx, my, op(0 if invalid), 0)
//   [2] = (c0, c1, c2, 0)
#define REC   12     // floats per gaussian
#define CHG   256    // gaussians per depth chunk (== blend block size)
#define SEG_L 256    // sort segment length (NJ = N/SEG_L = 8 partials)
#define GPRE  64     // gaussians per preprocess block (32 blocks for N=2048)

// ---------------------------------------------------------------------------
// Kernel A: role-split fused launch (roles have no data dependency):
//   blocks [0, NPRE)            : preprocess 64 gaussians each (CU spread)
//   blocks [NPRE, NPRE + NB*NJ) : sort partial-rank count (col, seg)
// Count computes tz directly from xyz+vm (6 flops), independent of the
// preprocess role's output -- that's what makes the fusion legal.
// ---------------------------------------------------------------------------
__global__ __launch_bounds__(256)
void pre_count_kernel(
    const float* __restrict__ xyz, const float* __restrict__ scaling,
    const float* __restrict__ rotation, const float* __restrict__ opacity,
    const float* __restrict__ fdc, const float* __restrict__ frest,
    const float* __restrict__ vm, const float* __restrict__ pm,
    const float* __restrict__ campos,
    const int* __restrict__ pH, const int* __restrict__ pW,
    float* __restrict__ pre, float4* __restrict__ bboxpre,
    int* __restrict__ rankpart, float* __restrict__ radii_out,
    int N, int NPRE, int NJ)
{
    __shared__ float s_fr[GPRE * 45];     // 11.5 KB (also aliased by count)
    const int tid = threadIdx.x;
    const int bid = blockIdx.x;

    if (bid >= NPRE) {
        // ================= role: sort partial-rank count =================
        float* s_tz = s_fr;               // alias (SEG_L floats used)
        int t = bid - NPRE;
        int col = t / NJ, seg = t - col * NJ;
        int base = seg * SEG_L;
        float c2 = vm[2], c6 = vm[6], c10 = vm[10], c14 = vm[14];
        if (tid < SEG_L) {
            int j = base + tid;
            s_tz[tid] = (j < N)
                ? xyz[j*3+0]*c2 + xyz[j*3+1]*c6 + xyz[j*3+2]*c10 + c14
                : 3.4e38f;
        }
        __syncthreads();

        int i = col * 256 + tid;
        if (i < N) {
            float key = xyz[i*3+0]*c2 + xyz[i*3+1]*c6 + xyz[i*3+2]*c10 + c14;
            int cnt = 0;
            #pragma unroll 8
            for (int j = 0; j < SEG_L; j += 4) {
                float4 v = *reinterpret_cast<float4*>(&s_tz[j]);
                cnt += (v.x < key) || (v.x == key && (base + j)     < i);
                cnt += (v.y < key) || (v.y == key && (base + j + 1) < i);
                cnt += (v.z < key) || (v.z == key && (base + j + 2) < i);
                cnt += (v.w < key) || (v.w == key && (base + j + 3) < i);
            }
            rankpart[seg * N + i] = cnt;
        }
        return;
    }

    // ================= role: preprocess (64 gaussians/block) =================
    int i0 = bid * GPRE;
    int cnt = N - i0; if (cnt > GPRE) cnt = GPRE;
    for (int t = tid; t < cnt * 45; t += 256)
        s_fr[t] = frest[(size_t)i0 * 45 + t];
    __syncthreads();

    if (tid >= GPRE) return;
    int i = i0 + tid;
    if (i >= N) return;
    float H = (float)*pH, W = (float)*pW;

    float px_ = xyz[i*3+0], py_ = xyz[i*3+1], pz_ = xyz[i*3+2];
    float s0 = expf(scaling[i*3+0]), s1 = expf(scaling[i*3+1]), s2 = expf(scaling[i*3+2]);
    float op = 1.f / (1.f + expf(-opacity[i]));

    float qw = rotation[i*4+0], qx = rotation[i*4+1], qy = rotation[i*4+2], qz = rotation[i*4+3];
    float qn = fmaxf(sqrtf(qw*qw + qx*qx + qy*qy + qz*qz), 1e-12f);
    qw /= qn; qx /= qn; qy /= qn; qz /= qn;

    float R00 = 1.f - 2.f*(qy*qy + qz*qz), R01 = 2.f*(qx*qy - qw*qz), R02 = 2.f*(qx*qz + qw*qy);
    float R10 = 2.f*(qx*qy + qw*qz), R11 = 1.f - 2.f*(qx*qx + qz*qz), R12 = 2.f*(qy*qz - qw*qx);
    float R20 = 2.f*(qx*qz - qw*qy), R21 = 2.f*(qy*qz + qw*qx), R22 = 1.f - 2.f*(qx*qx + qy*qy);

    float M00 = R00*s0, M01 = R01*s1, M02 = R02*s2;
    float M10 = R10*s0, M11 = R11*s1, M12 = R12*s2;
    float M20 = R20*s0, M21 = R21*s1, M22 = R22*s2;

    float S00 = M00*M00 + M01*M01 + M02*M02;
    float S01 = M00*M10 + M01*M11 + M02*M12;
    float S02 = M00*M20 + M01*M21 + M02*M22;
    float S11 = M10*M10 + M11*M11 + M12*M12;
    float S12 = M10*M20 + M11*M21 + M12*M22;
    float S22 = M20*M20 + M21*M21 + M22*M22;

    float t0 = px_*vm[0] + py_*vm[4] + pz_*vm[8]  + vm[12];
    float t1 = px_*vm[1] + py_*vm[5] + pz_*vm[9]  + vm[13];
    float tz = px_*vm[2] + py_*vm[6] + pz_*vm[10] + vm[14];

    float fx = W / (2.f * TANFOV), fy = H / (2.f * TANFOV);
    float lim = 1.3f * TANFOV;
    float tzs = (fabsf(tz) > 1e-6f) ? tz : 1e-6f;
    float txz = fminf(fmaxf(t0 / tzs, -lim), lim) * tzs;
    float tyz = fminf(fmaxf(t1 / tzs, -lim), lim) * tzs;
    float J00 = fx / tzs, J02 = -fx * txz / (tzs * tzs);
    float J11 = fy / tzs, J12 = -fy * tyz / (tzs * tzs);

    float T00 = J00*vm[0] + J02*vm[2];
    float T01 = J00*vm[4] + J02*vm[6];
    float T02 = J00*vm[8] + J02*vm[10];
    float T10 = J11*vm[1] + J12*vm[2];
    float T11 = J11*vm[5] + J12*vm[6];
    float T12 = J11*vm[9] + J12*vm[10];

    float u0 = S00*T00 + S01*T01 + S02*T02;
    float u1 = S01*T00 + S11*T01 + S12*T02;
    float u2 = S02*T00 + S12*T01 + S22*T02;
    float v0 = S00*T10 + S01*T11 + S02*T12;
    float v1 = S01*T10 + S11*T11 + S12*T12;
    float v2 = S02*T10 + S12*T11 + S22*T12;
    float a  = T00*u0 + T01*u1 + T02*u2 + 0.3f;
    float b  = T10*u0 + T11*u1 + T12*u2;
    float c  = T10*v0 + T11*v1 + T12*v2 + 0.3f;

    float det = a*c - b*b;
    bool valid = (tz > 0.2f) && (det > 0.f);
    float inv_det = 1.f / ((det > 0.f) ? det : 1.f);
    float conA = c * inv_det, conB = -b * inv_det, conC = a * inv_det;
    float mid = 0.5f * (a + c);
    float lam = mid + sqrtf(fmaxf(mid*mid - det, 0.1f));
    radii_out[i] = valid ? ceilf(3.f * sqrtf(lam)) : 0.f;

    float h0 = px_*pm[0] + py_*pm[4] + pz_*pm[8]  + pm[12];
    float h1 = px_*pm[1] + py_*pm[5] + pz_*pm[9]  + pm[13];
    float h3 = px_*pm[3] + py_*pm[7] + pz_*pm[11] + pm[15];
    float pw = 1.f / (h3 + 1e-7f);
    float mx = ((h0*pw + 1.f) * W - 1.f) * 0.5f;
    float my = ((h1*pw + 1.f) * H - 1.f) * 0.5f;

    float ddx = px_ - campos[0], ddy = py_ - campos[1], ddz = pz_ - campos[2];
    float dn = fmaxf(sqrtf(ddx*ddx + ddy*ddy + ddz*ddz), 1e-12f);
    float x = ddx/dn, y = ddy/dn, z = ddz/dn;
    float xx = x*x, yy = y*y, zz = z*z, xy = x*y, yz = y*z, xz = x*z;

    float basis[16];
    basis[0]  = 0.28209479177387814f;
    basis[1]  = -0.4886025119029199f * y;
    basis[2]  =  0.4886025119029199f * z;
    basis[3]  = -0.4886025119029199f * x;
    basis[4]  =  1.0925484305920792f * xy;
    basis[5]  = -1.0925484305920792f * yz;
    basis[6]  =  0.31539156525252005f * (2.f*zz - xx - yy);
    basis[7]  = -1.0925484305920792f * xz;
    basis[8]  =  0.5462742152960396f * (xx - yy);
    basis[9]  = -0.5900435899266435f * y * (3.f*xx - yy);
    basis[10] =  2.890611442640554f  * xy * z;
    basis[11] = -0.4570457994644658f * y * (4.f*zz - xx - yy);
    basis[12] =  0.3731763325901154f * z * (2.f*zz - 3.f*xx - 3.f*yy);
    basis[13] = -0.4570457994644658f * x * (4.f*zz - xx - yy);
    basis[14] =  1.445305721320277f  * z * (xx - yy);
    basis[15] = -0.5900435899266435f * x * (xx - 3.f*yy);

    const float* fr = &s_fr[tid * 45];
    float col[3];
    #pragma unroll
    for (int ch = 0; ch < 3; ++ch) {
        float r = basis[0] * fdc[i*3 + ch];
        #pragma unroll
        for (int j = 1; j < 16; ++j)
            r += basis[j] * fr[(j-1)*3 + ch];
        col[ch] = fmaxf(r + 0.5f, 0.f);
    }

    float opv = valid ? op : 0.f;
    float4* rec = (float4*)(pre + (size_t)i * REC);
    rec[0] = make_float4(tz, -0.5f*conA, -conB, -0.5f*conC);
    rec[1] = make_float4(mx, my, opv, 0.f);
    rec[2] = make_float4(col[0], col[1], col[2], 0.f);

    float4 bb;
    if (opv > 1.f/255.f) {
        float Rr = 1.01f * sqrtf(2.f * logf(255.f * opv) * lam) + 1.f;
        bb = make_float4(mx - Rr, mx + Rr, my - Rr, my + Rr);
    } else {
        bb = make_float4(1e30f, -1e30f, 1e30f, -1e30f);   // empty
    }
    bboxpre[i] = bb;
}

// ---------------------------------------------------------------------------
// Kernel B: rank sum -> permutation (perm[rank] = original index).
// ---------------------------------------------------------------------------
__global__ void scatter_kernel(const int* __restrict__ rankpart,
                               int* __restrict__ perm, int N, int NJ)
{
    int i = blockIdx.x * blockDim.x + threadIdx.x;
    if (i >= N) return;
    int rank = 0;
    for (int s = 0; s < NJ; ++s) rank += rankpart[s * N + i];
    perm[rank] = i;
}

// ---------------------------------------------------------------------------
// Kernel C: tile-cull blend. Block = (16x16 tile, 256-gaussian depth chunk).
// Phase A: thread t tests sorted slot g0+t: orig = perm[g], bbox gather,
// ballot-compact survivor ORIGINAL indices in depth order. Phase B: stage
// survivor records from pre (parallel gathers). Blend per pixel over
// survivors; write chunk partials.
// part layout: field*(G*HW) + chunk*HW + pix; fields 0..2 color, 3 depth, 4 T
// ---------------------------------------------------------------------------
__global__ __launch_bounds__(256)
void blend1_kernel(const float4* __restrict__ grec,
                   const float4* __restrict__ bbox,
                   const int* __restrict__ perm,
                   const int* __restrict__ pW,
                   float* __restrict__ part,
                   int N, int HW, int G)
{
    __shared__ int    s_cnt[4];
    __shared__ int    s_idx[CHG];
    __shared__ float4 s_rec[3 * CHG];

    int tid = threadIdx.x;
    int W = *pW;
    int tilesX = (W + 15) >> 4;
    int tileX = blockIdx.x % tilesX;
    int tileY = blockIdx.x / tilesX;
    int px = (tileX << 4) + (tid & 15);
    int py = (tileY << 4) + (tid >> 4);
    int pix = py * W + px;
    float fpx = (float)px, fpy = (float)py;
    float ftx0 = (float)(tileX << 4), ftx1 = ftx0 + 15.f;
    float fty0 = (float)(tileY << 4), fty1 = fty0 + 15.f;

    int chunk = blockIdx.y;
    int g0 = chunk * CHG;
    int S = G * HW;

    // ---- Phase A: cull (depth-ordered via perm) ----
    int g = g0 + tid;
    bool hit = false;
    int orig = 0;
    if (g < N) {
        orig = perm[g];                      // coalesced int load
        float4 bb = bbox[orig];              // gathered 16B load (L2)
        hit = (bb.x <= ftx1) && (bb.y >= ftx0) &&
              (bb.z <= fty1) && (bb.w >= fty0);
    }
    unsigned long long m = __ballot(hit);
    int lane = tid & 63, wv = tid >> 6;
    int pos = __popcll(m & ((1ull << lane) - 1ull));
    if (lane == 0) s_cnt[wv] = __popcll(m);
    __syncthreads();
    int total = s_cnt[0] + s_cnt[1] + s_cnt[2] + s_cnt[3];
    int off = 0;
    for (int w = 0; w < wv; ++w) off += s_cnt[w];
    if (hit) s_idx[off + pos] = orig;
    __syncthreads();

    // ---- Phase B: stage survivor records (parallel gathers) ----
    for (int k = tid; k < 3 * total; k += CHG) {
        int s = k / 3, e = k - 3 * s;
        s_rec[k] = grec[3 * s_idx[s] + e];
    }
    __syncthreads();

    // ---- blend over survivors (depth order preserved) ----
    float T = 1.f, c0 = 0.f, c1 = 0.f, c2 = 0.f, d = 0.f;
    for (int s = 0; s < total; ++s) {
        float4 pA = s_rec[3*s+0];   // tz, a2, b2, c2
        float4 pB = s_rec[3*s+1];   // mx, my, op, -
        float4 pC = s_rec[3*s+2];   // rgb
        float dx = fpx - pB.x, dy = fpy - pB.y;
        float power = pA.y*dx*dx + pA.w*dy*dy + pA.z*dx*dy;
        float alpha = fminf(0.99f, pB.z * __expf(fminf(power, 0.f)));
        bool keep = (power <= 0.f) && (alpha >= 1.f/255.f);
        float aeff = keep ? alpha : 0.f;
        float w = aeff * T;
        c0 = fmaf(w, pC.x, c0);
        c1 = fmaf(w, pC.y, c1);
        c2 = fmaf(w, pC.z, c2);
        d  = fmaf(w, pA.x, d);
        T  = T - aeff * T;
    }
    if (pix < HW) {
        int o = chunk * HW + pix;
        part[0*S+o] = c0; part[1*S+o] = c1; part[2*S+o] = c2;
        part[3*S+o] = d;  part[4*S+o] = T;
    }
}

// ---------------------------------------------------------------------------
// Kernel D: combine chunks per pixel, write final outputs.
// out layout: color[3][HW], depth[HW], amap[HW]  (radii written by kernel A)
// ---------------------------------------------------------------------------
__global__ void blend2_kernel(const float* __restrict__ part,
                              const float* __restrict__ bg,
                              float* __restrict__ out, int HW, int G)
{
    int pix = blockIdx.x * blockDim.x + threadIdx.x;
    if (pix >= HW) return;
    int S = G * HW;
    float T = 1.f, c0 = 0.f, c1 = 0.f, c2 = 0.f, d = 0.f;
    for (int k = 0; k < G; ++k) {
        int o = k * HW + pix;
        c0 += T * part[0*S+o];
        c1 += T * part[1*S+o];
        c2 += T * part[2*S+o];
        d  += T * part[3*S+o];
        T  *= part[4*S+o];
    }
    out[0*HW+pix] = c0 + T*bg[0];
    out[1*HW+pix] = c1 + T*bg[1];
    out[2*HW+pix] = c2 + T*bg[2];
    out[3*HW+pix] = d;
    out[4*HW+pix] = 1.f - T;
}

extern "C" void kernel_launch(void* const* d_in, const int* in_sizes, int n_in,
                              void* d_out, int out_size, void* d_ws, size_t ws_size,
                              hipStream_t stream) {
    const float* xyz      = (const float*)d_in[0];
    const float* scaling  = (const float*)d_in[1];
    const float* rotation = (const float*)d_in[2];
    const float* opacity  = (const float*)d_in[3];
    const float* fdc      = (const float*)d_in[4];
    const float* frest    = (const float*)d_in[5];
    const float* vm       = (const float*)d_in[6];
    const float* pm       = (const float*)d_in[7];
    const float* campos   = (const float*)d_in[8];
    const float* bg       = (const float*)d_in[9];
    const int*   pH       = (const int*)d_in[10];
    const int*   pW       = (const int*)d_in[11];

    int N    = in_sizes[0] / 3;
    int HW   = (out_size - N) / 5;
    int G    = (N + CHG - 1) / CHG;       // 8 chunks
    int NJ   = (N + SEG_L - 1) / SEG_L;   // 8 segments
    int NB   = (N + 255) / 256;           // 8 count columns
    int NPRE = (N + GPRE - 1) / GPRE;     // 32 preprocess blocks
    int NT   = (HW + 255) / 256;          // 64 tiles

    // ws layout:
    //   pre     : REC*N floats
    //   bboxpre : 4*N floats
    //   rankpart: NJ*N ints
    //   perm    : N ints
    //   part    : 5*G*HW floats
    float*  ws       = (float*)d_ws;
    float*  pre      = ws;
    float4* bboxpre  = (float4*)(pre + (size_t)REC * N);
    int*    rankpart = (int*)(bboxpre + N);
    int*    perm     = rankpart + (size_t)NJ * N;
    float*  part     = (float*)(perm + N);

    float* out   = (float*)d_out;
    float* radii = out + (size_t)5 * HW;

    // Kernel A: preprocess (blocks 0..NPRE-1) || count (NPRE..NPRE+NB*NJ-1)
    pre_count_kernel<<<NPRE + NB * NJ, 256, 0, stream>>>(
        xyz, scaling, rotation, opacity, fdc, frest, vm, pm, campos, pH, pW,
        pre, bboxpre, rankpart, radii, N, NPRE, NJ);
    // Kernel B: ranks -> permutation
    scatter_kernel<<<NB, 256, 0, stream>>>(rankpart, perm, N, NJ);
    // Kernel C: tile-cull blend
    dim3 bgrid(NT, G);
    blend1_kernel<<<bgrid, CHG, 0, stream>>>(
        (const float4*)pre, bboxpre, perm, pW, part, N, HW, G);
    // Kernel D: combine
    blend2_kernel<<<NT, 256, 0, stream>>>(part, bg, out, HW, G);
}

// Round 14
// 28.833 us; speedup vs baseline: 3.6158x; 1.1779x over previous
//
#include <hip/hip_runtime.h>
#include <math.h>

#define TANFOV 1.0f

// AoS gaussian record: 3 x float4 (ORIGINAL gaussian order; depth order via
// the perm[] index array built by scatter_kernel)
//   [0] = (tz, -0.5*conA, -conB, -0.5*conC)
//   [1] = (mx, my, op(0 if invalid), 0)
//   [2] = (c0, c1, c2, 0)
#define REC   12     // floats per gaussian
#define CHG   256    // gaussians per depth chunk (== one wave's window)
#define SEG_L 128    // sort segment length (NJ = 16)
#define MAXW  8      // max depth chunks / waves per render block

// ---------------------------------------------------------------------------
// Kernel A: role-split fused launch (no data dependency between roles):
//   blocks [0, NB)           : preprocess 256 gaussians each
//   blocks [NB, NB + NB*NJ)  : sort partial-rank count (col, seg)
// Count computes tz directly from xyz+vm (6 flops) instead of depending on
// preprocess output -- this is what makes the fusion legal.  (R9-identical.)
// ---------------------------------------------------------------------------
__global__ __launch_bounds__(256)
void pre_count_kernel(
    const float* __restrict__ xyz, const float* __restrict__ scaling,
    const float* __restrict__ rotation, const float* __restrict__ opacity,
    const float* __restrict__ fdc, const float* __restrict__ frest,
    const float* __restrict__ vm, const float* __restrict__ pm,
    const float* __restrict__ campos,
    const int* __restrict__ pH, const int* __restrict__ pW,
    float* __restrict__ pre, float4* __restrict__ bboxpre,
    int* __restrict__ rankpart, float* __restrict__ radii_out,
    int N, int NB, int NJ)
{
    __shared__ float s_fr[256 * 45];      // preprocess: frest staging (46 KB)
    const int tid = threadIdx.x;
    const int bid = blockIdx.x;

    if (bid >= NB) {
        // ================= role: sort partial-rank count =================
        float* s_tz = s_fr;               // alias (only SEG_L floats used)
        int t = bid - NB;
        int col = t / NJ, seg = t - col * NJ;
        int base = seg * SEG_L;
        float c2 = vm[2], c6 = vm[6], c10 = vm[10], c14 = vm[14];
        if (tid < SEG_L) {
            int j = base + tid;
            s_tz[tid] = (j < N)
                ? xyz[j*3+0]*c2 + xyz[j*3+1]*c6 + xyz[j*3+2]*c10 + c14
                : 3.4e38f;
        }
        __syncthreads();

        int i = col * 256 + tid;
        if (i < N) {
            float key = xyz[i*3+0]*c2 + xyz[i*3+1]*c6 + xyz[i*3+2]*c10 + c14;
            int cnt = 0;
            #pragma unroll 8
            for (int j = 0; j < SEG_L; j += 4) {
                float4 v = *reinterpret_cast<float4*>(&s_tz[j]);
                cnt += (v.x < key) || (v.x == key && (base + j)     < i);
                cnt += (v.y < key) || (v.y == key && (base + j + 1) < i);
                cnt += (v.z < key) || (v.z == key && (base + j + 2) < i);
                cnt += (v.w < key) || (v.w == key && (base + j + 3) < i);
            }
            rankpart[seg * N + i] = cnt;
        }
        return;
    }

    // ================= role: preprocess =================
    int i0 = bid * 256;
    int cnt = N - i0; if (cnt > 256) cnt = 256;
    for (int t = tid; t < cnt * 45; t += 256)
        s_fr[t] = frest[(size_t)i0 * 45 + t];
    __syncthreads();

    int i = i0 + tid;
    if (i >= N) return;
    float H = (float)*pH, W = (float)*pW;

    float px_ = xyz[i*3+0], py_ = xyz[i*3+1], pz_ = xyz[i*3+2];
    float s0 = expf(scaling[i*3+0]), s1 = expf(scaling[i*3+1]), s2 = expf(scaling[i*3+2]);
    float op = 1.f / (1.f + expf(-opacity[i]));

    float qw = rotation[i*4+0], qx = rotation[i*4+1], qy = rotation[i*4+2], qz = rotation[i*4+3];
    float qn = fmaxf(sqrtf(qw*qw + qx*qx + qy*qy + qz*qz), 1e-12f);
    qw /= qn; qx /= qn; qy /= qn; qz /= qn;

    float R00 = 1.f - 2.f*(qy*qy + qz*qz), R01 = 2.f*(qx*qy - qw*qz), R02 = 2.f*(qx*qz + qw*qy);
    float R10 = 2.f*(qx*qy + qw*qz), R11 = 1.f - 2.f*(qx*qx + qz*qz), R12 = 2.f*(qy*qz - qw*qx);
    float R20 = 2.f*(qx*qz - qw*qy), R21 = 2.f*(qy*qz + qw*qx), R22 = 1.f - 2.f*(qx*qx + qy*qy);

    float M00 = R00*s0, M01 = R01*s1, M02 = R02*s2;
    float M10 = R10*s0, M11 = R11*s1, M12 = R12*s2;
    float M20 = R20*s0, M21 = R21*s1, M22 = R22*s2;

    float S00 = M00*M00 + M01*M01 + M02*M02;
    float S01 = M00*M10 + M01*M11 + M02*M12;
    float S02 = M00*M20 + M01*M21 + M02*M22;
    float S11 = M10*M10 + M11*M11 + M12*M12;
    float S12 = M10*M20 + M11*M21 + M12*M22;
    float S22 = M20*M20 + M21*M21 + M22*M22;

    float t0 = px_*vm[0] + py_*vm[4] + pz_*vm[8]  + vm[12];
    float t1 = px_*vm[1] + py_*vm[5] + pz_*vm[9]  + vm[13];
    float tz = px_*vm[2] + py_*vm[6] + pz_*vm[10] + vm[14];

    float fx = W / (2.f * TANFOV), fy = H / (2.f * TANFOV);
    float lim = 1.3f * TANFOV;
    float tzs = (fabsf(tz) > 1e-6f) ? tz : 1e-6f;
    float txz = fminf(fmaxf(t0 / tzs, -lim), lim) * tzs;
    float tyz = fminf(fmaxf(t1 / tzs, -lim), lim) * tzs;
    float J00 = fx / tzs, J02 = -fx * txz / (tzs * tzs);
    float J11 = fy / tzs, J12 = -fy * tyz / (tzs * tzs);

    float T00 = J00*vm[0] + J02*vm[2];
    float T01 = J00*vm[4] + J02*vm[6];
    float T02 = J00*vm[8] + J02*vm[10];
    float T10 = J11*vm[1] + J12*vm[2];
    float T11 = J11*vm[5] + J12*vm[6];
    float T12 = J11*vm[9] + J12*vm[10];

    float u0 = S00*T00 + S01*T01 + S02*T02;
    float u1 = S01*T00 + S11*T01 + S12*T02;
    float u2 = S02*T00 + S12*T01 + S22*T02;
    float v0 = S00*T10 + S01*T11 + S02*T12;
    float v1 = S01*T10 + S11*T11 + S12*T12;
    float v2 = S02*T10 + S12*T11 + S22*T12;
    float a  = T00*u0 + T01*u1 + T02*u2 + 0.3f;
    float b  = T10*u0 + T11*u1 + T12*u2;
    float c  = T10*v0 + T11*v1 + T12*v2 + 0.3f;

    float det = a*c - b*b;
    bool valid = (tz > 0.2f) && (det > 0.f);
    float inv_det = 1.f / ((det > 0.f) ? det : 1.f);
    float conA = c * inv_det, conB = -b * inv_det, conC = a * inv_det;
    float mid = 0.5f * (a + c);
    float lam = mid + sqrtf(fmaxf(mid*mid - det, 0.1f));
    radii_out[i] = valid ? ceilf(3.f * sqrtf(lam)) : 0.f;

    float h0 = px_*pm[0] + py_*pm[4] + pz_*pm[8]  + pm[12];
    float h1 = px_*pm[1] + py_*pm[5] + pz_*pm[9]  + pm[13];
    float h3 = px_*pm[3] + py_*pm[7] + pz_*pm[11] + pm[15];
    float pw = 1.f / (h3 + 1e-7f);
    float mx = ((h0*pw + 1.f) * W - 1.f) * 0.5f;
    float my = ((h1*pw + 1.f) * H - 1.f) * 0.5f;

    float ddx = px_ - campos[0], ddy = py_ - campos[1], ddz = pz_ - campos[2];
    float dn = fmaxf(sqrtf(ddx*ddx + ddy*ddy + ddz*ddz), 1e-12f);
    float x = ddx/dn, y = ddy/dn, z = ddz/dn;
    float xx = x*x, yy = y*y, zz = z*z, xy = x*y, yz = y*z, xz = x*z;

    float basis[16];
    basis[0]  = 0.28209479177387814f;
    basis[1]  = -0.4886025119029199f * y;
    basis[2]  =  0.4886025119029199f * z;
    basis[3]  = -0.4886025119029199f * x;
    basis[4]  =  1.0925484305920792f * xy;
    basis[5]  = -1.0925484305920792f * yz;
    basis[6]  =  0.31539156525252005f * (2.f*zz - xx - yy);
    basis[7]  = -1.0925484305920792f * xz;
    basis[8]  =  0.5462742152960396f * (xx - yy);
    basis[9]  = -0.5900435899266435f * y * (3.f*xx - yy);
    basis[10] =  2.890611442640554f  * xy * z;
    basis[11] = -0.4570457994644658f * y * (4.f*zz - xx - yy);
    basis[12] =  0.3731763325901154f * z * (2.f*zz - 3.f*xx - 3.f*yy);
    basis[13] = -0.4570457994644658f * x * (4.f*zz - xx - yy);
    basis[14] =  1.445305721320277f  * z * (xx - yy);
    basis[15] = -0.5900435899266435f * x * (xx - 3.f*yy);

    const float* fr = &s_fr[tid * 45];
    float col[3];
    #pragma unroll
    for (int ch = 0; ch < 3; ++ch) {
        float r = basis[0] * fdc[i*3 + ch];
        #pragma unroll
        for (int j = 1; j < 16; ++j)
            r += basis[j] * fr[(j-1)*3 + ch];
        col[ch] = fmaxf(r + 0.5f, 0.f);
    }

    float opv = valid ? op : 0.f;
    float4* rec = (float4*)(pre + (size_t)i * REC);
    rec[0] = make_float4(tz, -0.5f*conA, -conB, -0.5f*conC);
    rec[1] = make_float4(mx, my, opv, 0.f);
    rec[2] = make_float4(col[0], col[1], col[2], 0.f);

    float4 bb;
    if (opv > 1.f/255.f) {
        float Rr = 1.01f * sqrtf(2.f * logf(255.f * opv) * lam) + 1.f;
        bb = make_float4(mx - Rr, mx + Rr, my - Rr, my + Rr);
    } else {
        bb = make_float4(1e30f, -1e30f, 1e30f, -1e30f);   // empty
    }
    bboxpre[i] = bb;
}

// ---------------------------------------------------------------------------
// Kernel B: rank sum -> permutation (perm[rank] = original index).
// ---------------------------------------------------------------------------
__global__ void scatter_kernel(const int* __restrict__ rankpart,
                               int* __restrict__ perm, int N, int NJ)
{
    int i = blockIdx.x * blockDim.x + threadIdx.x;
    if (i >= N) return;
    int rank = 0;
    for (int s = 0; s < NJ; ++s) rank += rankpart[s * N + i];
    perm[rank] = i;
}

// ---------------------------------------------------------------------------
// Kernel C: fused blend + combine. Block = one 8x8 pixel tile, G waves;
// wave w owns depth chunk w (gaussians [w*256, (w+1)*256) in sorted order).
// Each wave independently: culls its window vs the tile (ballot-compact,
// depth order preserved), stages survivors to its private LDS region in
// 64-record batches, and blends its 64 pixels into registers. NO cross-wave
// sync in this phase (divergent batch counts are safe; all LDS regions are
// wave-private). Then one __syncthreads() and wave 0 combines the G chunk
// partials per pixel front-to-back and writes final color/depth/amap.
// Eliminates the part[] global buffer and the separate combine launch.
// ---------------------------------------------------------------------------
__global__ __launch_bounds__(512)
void blend_fused_kernel(const float4* __restrict__ grec,
                        const float4* __restrict__ bbox,
                        const int* __restrict__ perm,
                        const int* __restrict__ pW,
                        const float* __restrict__ bg,
                        float* __restrict__ out,
                        int N, int HW, int G)
{
    __shared__ int    s_idx[MAXW][CHG];       // survivor orig-indices per wave
    __shared__ float4 s_rec[MAXW][3 * 64];    // staged records per wave
    __shared__ float  s_part[MAXW][5][64];    // per-wave partials

    const int tid = threadIdx.x;
    const int w = tid >> 6;                   // wave id == depth chunk id
    const int l = tid & 63;                   // lane id == pixel id in tile

    int W = *pW;
    int tilesX = W >> 3;
    int tileX = blockIdx.x % tilesX;
    int tileY = blockIdx.x / tilesX;
    int px = (tileX << 3) + (l & 7);
    int py = (tileY << 3) + (l >> 3);
    int pix = py * W + px;
    float fpx = (float)px, fpy = (float)py;
    float ftx0 = (float)(tileX << 3), ftx1 = ftx0 + 7.f;
    float fty0 = (float)(tileY << 3), fty1 = fty0 + 7.f;

    // ---- cull chunk w: 4 rounds of 64, ballot-compact (depth order) ----
    int K = 0;
    int g0 = w * CHG;
    #pragma unroll
    for (int it = 0; it < CHG / 64; ++it) {
        int g = g0 + (it << 6) + l;
        bool hit = false; int orig = 0;
        if (g < N) {
            orig = perm[g];                  // coalesced int load
            float4 bb = bbox[orig];          // gathered 16B load (L2)
            hit = (bb.x <= ftx1) && (bb.y >= ftx0) &&
                  (bb.z <= fty1) && (bb.w >= fty0);
        }
        unsigned long long m = __ballot(hit);
        if (hit) {
            int pos = __popcll(m & ((1ull << l) - 1ull));
            s_idx[w][K + pos] = orig;
        }
        K += __popcll(m);
    }

    // ---- blend chunk w for this wave's 64 pixels, in 64-record batches ----
    float T = 1.f, c0 = 0.f, c1 = 0.f, c2 = 0.f, d = 0.f;
    for (int b0 = 0; b0 < K; b0 += 64) {
        int nb = K - b0; if (nb > 64) nb = 64;
        for (int k = l; k < 3 * nb; k += 64) {
            int s = k / 3, e = k - 3 * s;
            s_rec[w][k] = grec[3 * s_idx[w][b0 + s] + e];
        }
        __builtin_amdgcn_wave_barrier();     // keep compiler from reordering
        for (int s = 0; s < nb; ++s) {
            float4 pA = s_rec[w][3*s+0];     // tz, a2, b2, c2
            float4 pB = s_rec[w][3*s+1];     // mx, my, op, -
            float4 pC = s_rec[w][3*s+2];     // rgb
            float dx = fpx - pB.x, dy = fpy - pB.y;
            float power = pA.y*dx*dx + pA.w*dy*dy + pA.z*dx*dy;
            float alpha = fminf(0.99f, pB.z * __expf(fminf(power, 0.f)));
            bool keep = (power <= 0.f) && (alpha >= 1.f/255.f);
            float aeff = keep ? alpha : 0.f;
            float wt = aeff * T;
            c0 = fmaf(wt, pC.x, c0);
            c1 = fmaf(wt, pC.y, c1);
            c2 = fmaf(wt, pC.z, c2);
            d  = fmaf(wt, pA.x, d);
            T  = T - aeff * T;
        }
        __builtin_amdgcn_wave_barrier();
    }

    s_part[w][0][l] = c0; s_part[w][1][l] = c1; s_part[w][2][l] = c2;
    s_part[w][3][l] = d;  s_part[w][4][l] = T;
    __syncthreads();

    // ---- combine: wave 0, one pixel per lane, front-to-back over chunks ----
    if (w == 0 && pix < HW) {
        float Tc = 1.f, f0 = 0.f, f1 = 0.f, f2 = 0.f, fd = 0.f;
        for (int k = 0; k < G; ++k) {
            f0 += Tc * s_part[k][0][l];
            f1 += Tc * s_part[k][1][l];
            f2 += Tc * s_part[k][2][l];
            fd += Tc * s_part[k][3][l];
            Tc *= s_part[k][4][l];
        }
        out[0*HW+pix] = f0 + Tc*bg[0];
        out[1*HW+pix] = f1 + Tc*bg[1];
        out[2*HW+pix] = f2 + Tc*bg[2];
        out[3*HW+pix] = fd;
        out[4*HW+pix] = 1.f - Tc;
    }
}

extern "C" void kernel_launch(void* const* d_in, const int* in_sizes, int n_in,
                              void* d_out, int out_size, void* d_ws, size_t ws_size,
                              hipStream_t stream) {
    const float* xyz      = (const float*)d_in[0];
    const float* scaling  = (const float*)d_in[1];
    const float* rotation = (const float*)d_in[2];
    const float* opacity  = (const float*)d_in[3];
    const float* fdc      = (const float*)d_in[4];
    const float* frest    = (const float*)d_in[5];
    const float* vm       = (const float*)d_in[6];
    const float* pm       = (const float*)d_in[7];
    const float* campos   = (const float*)d_in[8];
    const float* bg       = (const float*)d_in[9];
    const int*   pH       = (const int*)d_in[10];
    const int*   pW       = (const int*)d_in[11];

    int N  = in_sizes[0] / 3;
    int HW = (out_size - N) / 5;
    int G  = (N + CHG - 1) / CHG;       // 8 chunks (== waves per block)
    int NJ = (N + SEG_L - 1) / SEG_L;   // 16 segments
    int NB = (N + 255) / 256;           // 8 columns
    int NTILE = HW / 64;                // 256 8x8 tiles

    // ws layout:
    //   pre     : REC*N floats
    //   bboxpre : 4*N floats
    //   rankpart: NJ*N ints
    //   perm    : N ints
    float*  ws       = (float*)d_ws;
    float*  pre      = ws;
    float4* bboxpre  = (float4*)(pre + (size_t)REC * N);
    int*    rankpart = (int*)(bboxpre + N);
    int*    perm     = rankpart + (size_t)NJ * N;

    float* out   = (float*)d_out;
    float* radii = out + (size_t)5 * HW;

    // Kernel A: preprocess (blocks 0..NB-1) || count (blocks NB..NB+NB*NJ-1)
    pre_count_kernel<<<NB + NB * NJ, 256, 0, stream>>>(
        xyz, scaling, rotation, opacity, fdc, frest, vm, pm, campos, pH, pW,
        pre, bboxpre, rankpart, radii, N, NB, NJ);
    // Kernel B: ranks -> permutation
    scatter_kernel<<<NB, 256, 0, stream>>>(rankpart, perm, N, NJ);
    // Kernel C: fused per-tile blend + in-block combine (G waves per block)
    blend_fused_kernel<<<NTILE, G * 64, 0, stream>>>(
        (const float4*)pre, bboxpre, perm, pW, bg, out, N, HW, G);
}